// Round 1
// baseline (108.578 us; speedup 1.0000x reference)
//
#include <hip/hip_runtime.h>
#include <hip/hip_bf16.h>

// LocalKNN: B=64, Way=5, D=64, Nq=1024 (32x32), Ns=1024, K=3.
// out[b,w] = sum_q sum(top3_s( <qhat_bq, shat_bws> ))

using bf16x8 = __attribute__((ext_vector_type(8))) short;  // 8 bf16 = 4 VGPRs
using f32x4  = __attribute__((ext_vector_type(4))) float;

__device__ inline unsigned short f2bf(float f) {
    unsigned int u = __float_as_uint(f);
    u += 0x7fffu + ((u >> 16) & 1u);   // round-to-nearest-even (inputs finite)
    return (unsigned short)(u >> 16);
}

__device__ inline uint4 pack8(const float* v) {
    uint4 r;
    r.x = (unsigned)f2bf(v[0]) | ((unsigned)f2bf(v[1]) << 16);
    r.y = (unsigned)f2bf(v[2]) | ((unsigned)f2bf(v[3]) << 16);
    r.z = (unsigned)f2bf(v[4]) | ((unsigned)f2bf(v[5]) << 16);
    r.w = (unsigned)f2bf(v[6]) | ((unsigned)f2bf(v[7]) << 16);
    return r;
}

// branchless insert of v into sorted top-3 (t0>=t1>=t2): 1 max + 2 med3
#define INS(v, T0, T1, T2) do {                         \
    float _v = (v);                                     \
    float _n0 = fmaxf((T0), _v);                        \
    float _n1 = __builtin_amdgcn_fmed3f(_v, (T0), (T1));\
    float _n2 = __builtin_amdgcn_fmed3f(_v, (T1), (T2));\
    (T0) = _n0; (T1) = _n1; (T2) = _n2;                 \
} while (0)

// ---------------- kernel 1: inverse L2 norms along D (stride 1024) ----------
// query: 64*1024 vectors, support: 64*5*1024 vectors; each dim-64, stride 1024.
__global__ void norms_kernel(const float* __restrict__ Q, const float* __restrict__ S,
                             float* __restrict__ rnq, float* __restrict__ rns) {
    int gid = blockIdx.x * blockDim.x + threadIdx.x;
    if (gid < 65536) {
        int b = gid >> 10, qi = gid & 1023;
        const float* p = Q + (size_t)b * 65536 + qi;
        float ss = 0.f;
        #pragma unroll
        for (int d = 0; d < 64; ++d) { float v = p[(size_t)d * 1024]; ss += v * v; }
        rnq[gid] = 1.0f / fmaxf(sqrtf(ss), 1e-12f);
    } else {
        int v = gid - 65536;                 // 0 .. 327679
        int bw = v >> 10, si = v & 1023;
        const float* p = S + (size_t)bw * 65536 + si;
        float ss = 0.f;
        #pragma unroll
        for (int d = 0; d < 64; ++d) { float x = p[(size_t)d * 1024]; ss += x * x; }
        rns[v] = 1.0f / fmaxf(sqrtf(ss), 1e-12f);
    }
}

// ---------------- kernel 2: fused GEMM + top-3 ------------------------------
// grid = (4 qchunks, 5 ways, 64 batch), block = 512 (8 waves).
// Wave wv owns q-tiles 2wv, 2wv+1 (32 q's). C = S_tile(16s x k) * Q_tile(k x 16q),
// so C col = lane&15 = q (lane-local top-3), C row = s.
// LDS fragment layout per 16-row tile: [h=0..7][r=0..15][16B], element (row=r,k=8h+j).
__global__ __launch_bounds__(512) void knn_main(
        const float* __restrict__ Q, const float* __restrict__ S,
        const float* __restrict__ rnq, const float* __restrict__ rns,
        float* __restrict__ partial) {
    __shared__ uint4 qfrag[16 * 128];      // 32 KB: 16 q-tiles
    __shared__ uint4 sfrag[2][4 * 128];    // 2 x 8 KB: double-buffered 64-s block
    __shared__ float wsum[8];

    const int qc = blockIdx.x, w = blockIdx.y, b = blockIdx.z;
    const int t = threadIdx.x, wv = t >> 6, lane = t & 63;

    const float* Qb   = Q + (size_t)b * 65536;            // (d,q) stride 1024 in d
    const float* Sb   = S + (size_t)(b * 5 + w) * 65536;  // (d,s) stride 1024 in d
    const float* rnqb = rnq + (b << 10);
    const float* rnsb = rns + ((b * 5 + w) << 10);

    // ---- stage Q chunk (256 q x 64 d) into fragment layout ----
    for (int sub = 0; sub < 4; ++sub) {
        int qg = (qc << 8) + (sub << 6) + lane;           // global q
        float r = rnqb[qg];
        float v[8];
        #pragma unroll
        for (int i = 0; i < 8; ++i)
            v[i] = Qb[(size_t)((wv << 3) + i) * 1024 + qg] * r;
        qfrag[((sub << 2) + (lane >> 4)) * 128 + (wv << 4) + (lane & 15)] = pack8(v);
    }
    __syncthreads();

    // ---- this wave's B fragments: 2 q-tiles x 2 k-halves ----
    bf16x8 bq[2][2];
    #pragma unroll
    for (int qt = 0; qt < 2; ++qt)
        #pragma unroll
        for (int c = 0; c < 2; ++c)
            bq[qt][c] = *reinterpret_cast<const bf16x8*>(
                &qfrag[((wv << 1) + qt) * 128 + (c << 6) + lane]);

    // ---- prologue: stage S block 0 ----
    {
        float sv[8]; float rs = rnsb[lane];
        #pragma unroll
        for (int i = 0; i < 8; ++i)
            sv[i] = Sb[(size_t)((wv << 3) + i) * 1024 + lane] * rs;
        sfrag[0][(lane >> 4) * 128 + (wv << 4) + (lane & 15)] = pack8(sv);
    }
    __syncthreads();

    float t0[2] = {-1e30f, -1e30f}, t1[2] = {-1e30f, -1e30f}, t2[2] = {-1e30f, -1e30f};
    int cur = 0;

    for (int blk = 0; blk < 16; ++blk) {
        // issue next block's global loads early (hide under MFMA+VALU)
        float sv[8];
        if (blk < 15) {
            const int sb = (blk + 1) << 6;
            float rs = rnsb[sb + lane];
            #pragma unroll
            for (int i = 0; i < 8; ++i)
                sv[i] = Sb[(size_t)((wv << 3) + i) * 1024 + sb + lane] * rs;
        }
        // compute on current buffer: 4 s-tiles x 2 q-tiles x (k=64)
        #pragma unroll
        for (int st = 0; st < 4; ++st) {
            bf16x8 a0 = *reinterpret_cast<const bf16x8*>(&sfrag[cur][st * 128 + lane]);
            bf16x8 a1 = *reinterpret_cast<const bf16x8*>(&sfrag[cur][st * 128 + 64 + lane]);
            #pragma unroll
            for (int qt = 0; qt < 2; ++qt) {
                f32x4 c = {0.f, 0.f, 0.f, 0.f};
                c = __builtin_amdgcn_mfma_f32_16x16x32_bf16(a0, bq[qt][0], c, 0, 0, 0);
                c = __builtin_amdgcn_mfma_f32_16x16x32_bf16(a1, bq[qt][1], c, 0, 0, 0);
                #pragma unroll
                for (int j = 0; j < 4; ++j)
                    INS(c[j], t0[qt], t1[qt], t2[qt]);
            }
        }
        if (blk < 15)
            sfrag[cur ^ 1][(lane >> 4) * 128 + (wv << 4) + (lane & 15)] = pack8(sv);
        __syncthreads();
        cur ^= 1;
    }

    // ---- merge top-3 across the 4 lane-groups sharing each q ----
    #pragma unroll
    for (int qt = 0; qt < 2; ++qt) {
        #pragma unroll
        for (int m = 16; m <= 32; m <<= 1) {
            float b0 = __shfl_xor(t0[qt], m);
            float b1 = __shfl_xor(t1[qt], m);
            float b2 = __shfl_xor(t2[qt], m);
            INS(b0, t0[qt], t1[qt], t2[qt]);
            INS(b1, t0[qt], t1[qt], t2[qt]);
            INS(b2, t0[qt], t1[qt], t2[qt]);
        }
    }
    // each lane: top-3 sums for its q in each of its 2 q-tiles (replicated x4)
    float s3 = (t0[0] + t1[0] + t2[0]) + (t0[1] + t1[1] + t2[1]);
    #pragma unroll
    for (int m = 1; m < 64; m <<= 1) s3 += __shfl_xor(s3, m);
    s3 *= 0.25f;                       // 4 identical copies per q were summed
    if (lane == 0) wsum[wv] = s3;
    __syncthreads();
    if (t == 0) {
        float acc = 0.f;
        #pragma unroll
        for (int i = 0; i < 8; ++i) acc += wsum[i];
        partial[((size_t)(b * 5 + w) << 2) + qc] = acc;
    }
}

// ---------------- kernel 3: deterministic final reduce ----------------------
__global__ void finalize_kernel(const float* __restrict__ partial, float* __restrict__ out) {
    int i = blockIdx.x * blockDim.x + threadIdx.x;
    if (i < 320)
        out[i] = (partial[4 * i] + partial[4 * i + 1]) +
                 (partial[4 * i + 2] + partial[4 * i + 3]);
}

extern "C" void kernel_launch(void* const* d_in, const int* in_sizes, int n_in,
                              void* d_out, int out_size, void* d_ws, size_t ws_size,
                              hipStream_t stream) {
    const float* Q = (const float*)d_in[0];   // (64,64,32,32)
    const float* S = (const float*)d_in[1];   // (64,5,64,1024)
    float* out = (float*)d_out;               // (64,5)

    // workspace: rnq 65536 f32 | rns 327680 f32 | partial 1280 f32  (~1.6 MB)
    float* rnq = (float*)d_ws;
    float* rns = rnq + 65536;
    float* partial = rns + 327680;

    norms_kernel<<<(65536 + 327680) / 256, 256, 0, stream>>>(Q, S, rnq, rns);
    dim3 grid(4, 5, 64);
    knn_main<<<grid, 512, 0, stream>>>(Q, S, rnq, rns, partial);
    finalize_kernel<<<2, 256, 0, stream>>>(partial, out);
}

// Round 2
// 100.003 us; speedup vs baseline: 1.0858x; 1.0858x over previous
//
#include <hip/hip_runtime.h>
#include <hip/hip_bf16.h>

// LocalKNN: B=64, Way=5, D=64, Nq=1024, Ns=1024, K=3.
// out[b,w] = sum_q rnq[q] * sum(top3_s( <q_bq, shat_bws> ))   (rnq deferred: >0 scale
// per q does not change the top-3 *selection* over s)

using bf16x8 = __attribute__((ext_vector_type(8))) short;  // 8 bf16 = 4 VGPRs
using f32x4  = __attribute__((ext_vector_type(4))) float;

__device__ inline unsigned cvt_pk_bf16(float lo, float hi) {
    unsigned r;
    asm("v_cvt_pk_bf16_f32 %0, %1, %2" : "=v"(r) : "v"(lo), "v"(hi));
    return r;
}

__device__ inline uint4 pack8cvt(const float* v) {
    uint4 r;
    r.x = cvt_pk_bf16(v[0], v[1]);
    r.y = cvt_pk_bf16(v[2], v[3]);
    r.z = cvt_pk_bf16(v[4], v[5]);
    r.w = cvt_pk_bf16(v[6], v[7]);
    return r;
}

// branchless insert of v into sorted top-3 (t0>=t1>=t2): 1 max + 2 med3
#define INS(v, T0, T1, T2) do {                         \
    float _v = (v);                                     \
    float _n0 = fmaxf((T0), _v);                        \
    float _n1 = __builtin_amdgcn_fmed3f(_v, (T0), (T1));\
    float _n2 = __builtin_amdgcn_fmed3f(_v, (T1), (T2));\
    (T0) = _n0; (T1) = _n1; (T2) = _n2;                 \
} while (0)

// ---------------- kernel 1: inverse L2 norms along D (stride 1024) ----------
__global__ void norms_kernel(const float* __restrict__ Q, const float* __restrict__ S,
                             float* __restrict__ rnq, float* __restrict__ rns) {
    int gid = blockIdx.x * blockDim.x + threadIdx.x;
    if (gid < 65536) {
        int b = gid >> 10, qi = gid & 1023;
        const float* p = Q + (size_t)b * 65536 + qi;
        float ss = 0.f;
        #pragma unroll
        for (int d = 0; d < 64; ++d) { float v = p[(size_t)d * 1024]; ss += v * v; }
        rnq[gid] = 1.0f / fmaxf(sqrtf(ss), 1e-12f);
    } else {
        int v = gid - 65536;                 // 0 .. 327679
        int bw = v >> 10, si = v & 1023;
        const float* p = S + (size_t)bw * 65536 + si;
        float ss = 0.f;
        #pragma unroll
        for (int d = 0; d < 64; ++d) { float x = p[(size_t)d * 1024]; ss += x * x; }
        rns[v] = 1.0f / fmaxf(sqrtf(ss), 1e-12f);
    }
}

// ---------------- kernel 2: fused GEMM + top-3 ------------------------------
// grid = (2 qchunks, 5 ways, 64 batch), block = 512 (8 waves).
// Each block: 512 q x 1024 s. Wave wv owns q [wv*64, wv*64+64) (4 q-tiles, held in regs).
// C = S_tile(16s x k) * Q_tile(k x 16q): C col = lane&15 = q -> lane-local top-3.
// LDS fragment layout per 16-row tile: uint4 slot h*16+r holds (row r, k=8h..8h+7).
__global__ __launch_bounds__(512, 4) void knn_main(
        const float* __restrict__ Q, const float* __restrict__ S,
        const float* __restrict__ rnq, const float* __restrict__ rns,
        float* __restrict__ partial) {
    __shared__ uint4 qfrag[16 * 128];      // 32 KB: 16 q-tiles (one staging phase)
    __shared__ uint4 sfrag[2][4 * 128];    // 2 x 8 KB: double-buffered 64-s block
    __shared__ float wsum[8];

    const int qc = blockIdx.x, w = blockIdx.y, b = blockIdx.z;
    const int t = threadIdx.x, wv = t >> 6, lane = t & 63;

    const float* Qb   = Q + (size_t)b * 65536;            // (d,q) stride 1024 in d
    const float* Sb   = S + (size_t)(b * 5 + w) * 65536;  // (d,s) stride 1024 in d
    const float* rnqb = rnq + (b << 10);
    const float* rnsb = rns + ((b * 5 + w) << 10);

    // ---- stage 512 q in two 256-q phases; each wave keeps its 4 q-tiles in regs ----
    bf16x8 bq[4][2];
    for (int ph = 0; ph < 2; ++ph) {
        for (int sub = 0; sub < 4; ++sub) {
            int qg = (qc << 9) + (ph << 8) + (sub << 6) + lane;   // global q (raw, no norm)
            float v[8];
            #pragma unroll
            for (int i = 0; i < 8; ++i)
                v[i] = Qb[(size_t)((wv << 3) + i) * 1024 + qg];
            qfrag[((sub << 2) + (lane >> 4)) * 128 + (wv << 4) + (lane & 15)] = pack8cvt(v);
        }
        __syncthreads();
        if ((wv >> 2) == ph) {
            #pragma unroll
            for (int qt = 0; qt < 4; ++qt)
                #pragma unroll
                for (int c = 0; c < 2; ++c)
                    bq[qt][c] = *reinterpret_cast<const bf16x8*>(
                        &qfrag[(((wv & 3) << 2) + qt) * 128 + (c << 6) + lane]);
        }
        __syncthreads();
    }

    // ---- prologue: stage S block 0 (normalized) ----
    {
        float sv[8]; float rs = rnsb[lane];
        #pragma unroll
        for (int i = 0; i < 8; ++i)
            sv[i] = Sb[(size_t)((wv << 3) + i) * 1024 + lane] * rs;
        sfrag[0][(lane >> 4) * 128 + (wv << 4) + (lane & 15)] = pack8cvt(sv);
    }
    __syncthreads();

    float t0[4], t1[4], t2[4];
    #pragma unroll
    for (int qt = 0; qt < 4; ++qt) { t0[qt] = -1e30f; t1[qt] = -1e30f; t2[qt] = -1e30f; }
    int cur = 0;

    const float* sp = Sb + ((wv << 3) << 10) + lane;   // wave's d-slice column base

    for (int blk = 0; blk < 16; ++blk) {
        // issue next block's global loads early (hide under MFMA+VALU)
        float sv[8]; float rs;
        if (blk < 15) {
            const int sb = (blk + 1) << 6;
            rs = rnsb[sb + lane];
            #pragma unroll
            for (int i = 0; i < 8; ++i)
                sv[i] = sp[(size_t)(i << 10) + sb];
        }
        // compute on current buffer: 4 s-tiles x 4 q-tiles x (k=64)
        #pragma unroll
        for (int st = 0; st < 4; ++st) {
            bf16x8 a0 = *reinterpret_cast<const bf16x8*>(&sfrag[cur][st * 128 + lane]);
            bf16x8 a1 = *reinterpret_cast<const bf16x8*>(&sfrag[cur][st * 128 + 64 + lane]);
            #pragma unroll
            for (int qt = 0; qt < 4; ++qt) {
                f32x4 c = {0.f, 0.f, 0.f, 0.f};
                c = __builtin_amdgcn_mfma_f32_16x16x32_bf16(a0, bq[qt][0], c, 0, 0, 0);
                c = __builtin_amdgcn_mfma_f32_16x16x32_bf16(a1, bq[qt][1], c, 0, 0, 0);
                #pragma unroll
                for (int j = 0; j < 4; ++j)
                    INS(c[j], t0[qt], t1[qt], t2[qt]);
            }
        }
        if (blk < 15) {
            #pragma unroll
            for (int i = 0; i < 8; ++i) sv[i] *= rs;
            sfrag[cur ^ 1][(lane >> 4) * 128 + (wv << 4) + (lane & 15)] = pack8cvt(sv);
        }
        __syncthreads();
        cur ^= 1;
    }

    // ---- merge top-3 across the 4 lane-groups sharing each q; apply rnq ----
    float s3 = 0.f;
    #pragma unroll
    for (int qt = 0; qt < 4; ++qt) {
        #pragma unroll
        for (int m = 16; m <= 32; m <<= 1) {
            float b0 = __shfl_xor(t0[qt], m);
            float b1 = __shfl_xor(t1[qt], m);
            float b2 = __shfl_xor(t2[qt], m);
            INS(b0, t0[qt], t1[qt], t2[qt]);
            INS(b1, t0[qt], t1[qt], t2[qt]);
            INS(b2, t0[qt], t1[qt], t2[qt]);
        }
        int qg = (qc << 9) + (wv << 6) + (qt << 4) + (lane & 15);
        s3 += (t0[qt] + t1[qt] + t2[qt]) * rnqb[qg];
    }
    // sum over lanes (each q's result replicated x4 across lane groups)
    #pragma unroll
    for (int m = 1; m < 64; m <<= 1) s3 += __shfl_xor(s3, m);
    s3 *= 0.25f;
    if (lane == 0) wsum[wv] = s3;
    __syncthreads();
    if (t == 0) {
        float acc = 0.f;
        #pragma unroll
        for (int i = 0; i < 8; ++i) acc += wsum[i];
        partial[((b * 5 + w) << 1) + qc] = acc;
    }
}

// ---------------- kernel 3: deterministic final reduce ----------------------
__global__ void finalize_kernel(const float* __restrict__ partial, float* __restrict__ out) {
    int i = blockIdx.x * blockDim.x + threadIdx.x;
    if (i < 320)
        out[i] = partial[2 * i] + partial[2 * i + 1];
}

extern "C" void kernel_launch(void* const* d_in, const int* in_sizes, int n_in,
                              void* d_out, int out_size, void* d_ws, size_t ws_size,
                              hipStream_t stream) {
    const float* Q = (const float*)d_in[0];   // (64,64,32,32)
    const float* S = (const float*)d_in[1];   // (64,5,64,1024)
    float* out = (float*)d_out;               // (64,5)

    // workspace: rnq 65536 f32 | rns 327680 f32 | partial 640 f32  (~1.6 MB)
    float* rnq = (float*)d_ws;
    float* rns = rnq + 65536;
    float* partial = rns + 327680;

    norms_kernel<<<(65536 + 327680) / 256, 256, 0, stream>>>(Q, S, rnq, rns);
    dim3 grid(2, 5, 64);
    knn_main<<<grid, 512, 0, stream>>>(Q, S, rnq, rns, partial);
    finalize_kernel<<<2, 256, 0, stream>>>(partial, out);
}

// Round 3
// 99.544 us; speedup vs baseline: 1.0908x; 1.0046x over previous
//
#include <hip/hip_runtime.h>
#include <hip/hip_bf16.h>

// LocalKNN: B=64, Way=5, D=64, Nq=1024, Ns=1024, K=3.
// out[b,w] = sum_q rnq[q] * sum(top3_s( <q_bq, shat_bws> ))
// Round 3: precompute bf16 MFMA fragments in ws; barrier-free LDS-free main loop.

using bf16x8 = __attribute__((ext_vector_type(8))) short;  // 8 bf16 = 4 VGPRs
using f32x4  = __attribute__((ext_vector_type(4))) float;

__device__ inline unsigned cvt_pk_bf16(float lo, float hi) {
    unsigned r;
    asm("v_cvt_pk_bf16_f32 %0, %1, %2" : "=v"(r) : "v"(lo), "v"(hi));
    return r;
}

__device__ inline uint4 pack8cvt(const float* v) {
    uint4 r;
    r.x = cvt_pk_bf16(v[0], v[1]);
    r.y = cvt_pk_bf16(v[2], v[3]);
    r.z = cvt_pk_bf16(v[4], v[5]);
    r.w = cvt_pk_bf16(v[6], v[7]);
    return r;
}

// branchless insert of v into sorted top-3 (t0>=t1>=t2): 1 max + 2 med3
#define INS(v, T0, T1, T2) do {                         \
    float _v = (v);                                     \
    float _n0 = fmaxf((T0), _v);                        \
    float _n1 = __builtin_amdgcn_fmed3f(_v, (T0), (T1));\
    float _n2 = __builtin_amdgcn_fmed3f(_v, (T1), (T2));\
    (T0) = _n0; (T1) = _n1; (T2) = _n2;                 \
} while (0)

// ============================= fast path =====================================
// Fragment layout (identical to the validated LDS layout): per 16-col tile,
// 128 uint4 slots; slot h*16 + r holds column (tile*16+r)'s elements
// d = 8h..8h+7 as 4 packed bf16-pairs. MFMA read: slot c*64 + lane ->
// lane holds col r=lane&15, k = c*32 + (lane>>4)*8 + j.

// ---- prep_q: raw Q -> bf16 fragments + rnq --------------------------------
__global__ __launch_bounds__(256) void prep_q(const float* __restrict__ Q,
                                              uint4* __restrict__ Qbf,
                                              float* __restrict__ rnq) {
    const int b = blockIdx.x >> 2;
    const int col = ((blockIdx.x & 3) << 8) + threadIdx.x;   // q in 0..1023
    const float* p = Q + (size_t)b * 65536 + col;
    float v[64];
    #pragma unroll
    for (int d = 0; d < 64; ++d) v[d] = p[(size_t)d << 10];
    float ss = 0.f;
    #pragma unroll
    for (int d = 0; d < 64; ++d) ss += v[d] * v[d];
    rnq[(b << 10) + col] = 1.0f / fmaxf(sqrtf(ss), 1e-12f);
    uint4* ob = Qbf + ((size_t)(b << 6) + (col >> 4)) * 128 + (col & 15);
    #pragma unroll
    for (int h = 0; h < 8; ++h)
        ob[h << 4] = pack8cvt(&v[h << 3]);
}

// ---- prep_s: normalized S -> bf16 fragments --------------------------------
__global__ __launch_bounds__(256) void prep_s(const float* __restrict__ S,
                                              uint4* __restrict__ Sbf) {
    const int bw = blockIdx.x >> 2;
    const int col = ((blockIdx.x & 3) << 8) + threadIdx.x;   // s in 0..1023
    const float* p = S + (size_t)bw * 65536 + col;
    float v[64];
    #pragma unroll
    for (int d = 0; d < 64; ++d) v[d] = p[(size_t)d << 10];
    float ss = 0.f;
    #pragma unroll
    for (int d = 0; d < 64; ++d) ss += v[d] * v[d];
    const float rs = 1.0f / fmaxf(sqrtf(ss), 1e-12f);
    #pragma unroll
    for (int d = 0; d < 64; ++d) v[d] *= rs;
    uint4* ob = Sbf + ((size_t)(bw << 6) + (col >> 4)) * 128 + (col & 15);
    #pragma unroll
    for (int h = 0; h < 8; ++h)
        ob[h << 4] = pack8cvt(&v[h << 3]);
}

// ---- main: barrier-free fused GEMM + top-3 ---------------------------------
// grid = (4 qchunks, 5 ways, 64 batch), block = 256 (4 waves).
// Wave wv owns q-tiles qc*16 + wv*4 + {0..3} (64 q) in registers; streams all
// 64 s-tiles. C = S_tile x Q_tile: col = lane&15 = q (lane-local top-3).
__global__ __launch_bounds__(256) void knn_main(const uint4* __restrict__ Qbf,
                                                const uint4* __restrict__ Sbf,
                                                const float* __restrict__ rnq,
                                                float* __restrict__ partial) {
    __shared__ float wsum[4];
    const int qc = blockIdx.x, w = blockIdx.y, b = blockIdx.z;
    const int wv = threadIdx.x >> 6, lane = threadIdx.x & 63;

    const uint4* qb = Qbf + ((size_t)(b << 6) + (qc << 4) + (wv << 2)) * 128 + lane;
    bf16x8 bq[4][2];
    #pragma unroll
    for (int qt = 0; qt < 4; ++qt)
        #pragma unroll
        for (int c = 0; c < 2; ++c)
            bq[qt][c] = *reinterpret_cast<const bf16x8*>(&qb[qt * 128 + (c << 6)]);

    const uint4* sb = Sbf + (size_t)((b * 5 + w) << 6) * 128 + lane;

    float t0[4], t1[4], t2[4];
    #pragma unroll
    for (int qt = 0; qt < 4; ++qt) { t0[qt] = -1e30f; t1[qt] = -1e30f; t2[qt] = -1e30f; }

    bf16x8 a0 = *reinterpret_cast<const bf16x8*>(&sb[0]);
    bf16x8 a1 = *reinterpret_cast<const bf16x8*>(&sb[64]);
    #pragma unroll 4
    for (int st = 0; st < 64; ++st) {
        const bf16x8 c0 = a0, c1 = a1;
        if (st < 63) {
            a0 = *reinterpret_cast<const bf16x8*>(&sb[(st + 1) * 128]);
            a1 = *reinterpret_cast<const bf16x8*>(&sb[(st + 1) * 128 + 64]);
        }
        #pragma unroll
        for (int qt = 0; qt < 4; ++qt) {
            f32x4 c = {0.f, 0.f, 0.f, 0.f};
            c = __builtin_amdgcn_mfma_f32_16x16x32_bf16(c0, bq[qt][0], c, 0, 0, 0);
            c = __builtin_amdgcn_mfma_f32_16x16x32_bf16(c1, bq[qt][1], c, 0, 0, 0);
            #pragma unroll
            for (int j = 0; j < 4; ++j)
                INS(c[j], t0[qt], t1[qt], t2[qt]);
        }
    }

    // merge top-3 across the 4 lane-groups sharing each q; apply rnq
    float s3 = 0.f;
    #pragma unroll
    for (int qt = 0; qt < 4; ++qt) {
        #pragma unroll
        for (int m = 16; m <= 32; m <<= 1) {
            float b0 = __shfl_xor(t0[qt], m);
            float b1 = __shfl_xor(t1[qt], m);
            float b2 = __shfl_xor(t2[qt], m);
            INS(b0, t0[qt], t1[qt], t2[qt]);
            INS(b1, t0[qt], t1[qt], t2[qt]);
            INS(b2, t0[qt], t1[qt], t2[qt]);
        }
        const int qg = (qc << 8) + (wv << 6) + (qt << 4) + (lane & 15);
        s3 += (t0[qt] + t1[qt] + t2[qt]) * rnq[(b << 10) + qg];
    }
    #pragma unroll
    for (int m = 1; m < 64; m <<= 1) s3 += __shfl_xor(s3, m);
    s3 *= 0.25f;                       // each q replicated over 4 lane-groups
    if (lane == 0) wsum[wv] = s3;
    __syncthreads();
    if (threadIdx.x == 0)
        partial[((b * 5 + w) << 2) + qc] = (wsum[0] + wsum[1]) + (wsum[2] + wsum[3]);
}

__global__ void finalize4(const float* __restrict__ partial, float* __restrict__ out) {
    int i = blockIdx.x * blockDim.x + threadIdx.x;
    if (i < 320)
        out[i] = (partial[4 * i] + partial[4 * i + 1]) +
                 (partial[4 * i + 2] + partial[4 * i + 3]);
}

// ============================ fallback path (round-2) ========================
__global__ void norms_kernel(const float* __restrict__ Q, const float* __restrict__ S,
                             float* __restrict__ rnq, float* __restrict__ rns) {
    int gid = blockIdx.x * blockDim.x + threadIdx.x;
    if (gid < 65536) {
        int b = gid >> 10, qi = gid & 1023;
        const float* p = Q + (size_t)b * 65536 + qi;
        float ss = 0.f;
        #pragma unroll
        for (int d = 0; d < 64; ++d) { float v = p[(size_t)d * 1024]; ss += v * v; }
        rnq[gid] = 1.0f / fmaxf(sqrtf(ss), 1e-12f);
    } else {
        int v = gid - 65536;
        int bw = v >> 10, si = v & 1023;
        const float* p = S + (size_t)bw * 65536 + si;
        float ss = 0.f;
        #pragma unroll
        for (int d = 0; d < 64; ++d) { float x = p[(size_t)d * 1024]; ss += x * x; }
        rns[v] = 1.0f / fmaxf(sqrtf(ss), 1e-12f);
    }
}

__global__ __launch_bounds__(512, 4) void knn_fb(
        const float* __restrict__ Q, const float* __restrict__ S,
        const float* __restrict__ rnq, const float* __restrict__ rns,
        float* __restrict__ partial) {
    __shared__ uint4 qfrag[16 * 128];
    __shared__ uint4 sfrag[2][4 * 128];
    __shared__ float wsum[8];

    const int qc = blockIdx.x, w = blockIdx.y, b = blockIdx.z;
    const int t = threadIdx.x, wv = t >> 6, lane = t & 63;

    const float* Qb   = Q + (size_t)b * 65536;
    const float* Sb   = S + (size_t)(b * 5 + w) * 65536;
    const float* rnqb = rnq + (b << 10);
    const float* rnsb = rns + ((b * 5 + w) << 10);

    bf16x8 bq[4][2];
    for (int ph = 0; ph < 2; ++ph) {
        for (int sub = 0; sub < 4; ++sub) {
            int qg = (qc << 9) + (ph << 8) + (sub << 6) + lane;
            float v[8];
            #pragma unroll
            for (int i = 0; i < 8; ++i)
                v[i] = Qb[(size_t)((wv << 3) + i) * 1024 + qg];
            qfrag[((sub << 2) + (lane >> 4)) * 128 + (wv << 4) + (lane & 15)] = pack8cvt(v);
        }
        __syncthreads();
        if ((wv >> 2) == ph) {
            #pragma unroll
            for (int qt = 0; qt < 4; ++qt)
                #pragma unroll
                for (int c = 0; c < 2; ++c)
                    bq[qt][c] = *reinterpret_cast<const bf16x8*>(
                        &qfrag[(((wv & 3) << 2) + qt) * 128 + (c << 6) + lane]);
        }
        __syncthreads();
    }

    {
        float sv[8]; float rs = rnsb[lane];
        #pragma unroll
        for (int i = 0; i < 8; ++i)
            sv[i] = Sb[(size_t)((wv << 3) + i) * 1024 + lane] * rs;
        sfrag[0][(lane >> 4) * 128 + (wv << 4) + (lane & 15)] = pack8cvt(sv);
    }
    __syncthreads();

    float t0[4], t1[4], t2[4];
    #pragma unroll
    for (int qt = 0; qt < 4; ++qt) { t0[qt] = -1e30f; t1[qt] = -1e30f; t2[qt] = -1e30f; }
    int cur = 0;
    const float* sp = Sb + ((wv << 3) << 10) + lane;

    for (int blk = 0; blk < 16; ++blk) {
        float sv[8]; float rs;
        if (blk < 15) {
            const int sb_ = (blk + 1) << 6;
            rs = rnsb[sb_ + lane];
            #pragma unroll
            for (int i = 0; i < 8; ++i)
                sv[i] = sp[(size_t)(i << 10) + sb_];
        }
        #pragma unroll
        for (int st = 0; st < 4; ++st) {
            bf16x8 a0 = *reinterpret_cast<const bf16x8*>(&sfrag[cur][st * 128 + lane]);
            bf16x8 a1 = *reinterpret_cast<const bf16x8*>(&sfrag[cur][st * 128 + 64 + lane]);
            #pragma unroll
            for (int qt = 0; qt < 4; ++qt) {
                f32x4 c = {0.f, 0.f, 0.f, 0.f};
                c = __builtin_amdgcn_mfma_f32_16x16x32_bf16(a0, bq[qt][0], c, 0, 0, 0);
                c = __builtin_amdgcn_mfma_f32_16x16x32_bf16(a1, bq[qt][1], c, 0, 0, 0);
                #pragma unroll
                for (int j = 0; j < 4; ++j)
                    INS(c[j], t0[qt], t1[qt], t2[qt]);
            }
        }
        if (blk < 15) {
            #pragma unroll
            for (int i = 0; i < 8; ++i) sv[i] *= rs;
            sfrag[cur ^ 1][(lane >> 4) * 128 + (wv << 4) + (lane & 15)] = pack8cvt(sv);
        }
        __syncthreads();
        cur ^= 1;
    }

    float s3 = 0.f;
    #pragma unroll
    for (int qt = 0; qt < 4; ++qt) {
        #pragma unroll
        for (int m = 16; m <= 32; m <<= 1) {
            float b0 = __shfl_xor(t0[qt], m);
            float b1 = __shfl_xor(t1[qt], m);
            float b2 = __shfl_xor(t2[qt], m);
            INS(b0, t0[qt], t1[qt], t2[qt]);
            INS(b1, t0[qt], t1[qt], t2[qt]);
            INS(b2, t0[qt], t1[qt], t2[qt]);
        }
        int qg = (qc << 9) + (wv << 6) + (qt << 4) + (lane & 15);
        s3 += (t0[qt] + t1[qt] + t2[qt]) * rnqb[qg];
    }
    #pragma unroll
    for (int m = 1; m < 64; m <<= 1) s3 += __shfl_xor(s3, m);
    s3 *= 0.25f;
    if (lane == 0) wsum[wv] = s3;
    __syncthreads();
    if (t == 0) {
        float acc = 0.f;
        #pragma unroll
        for (int i = 0; i < 8; ++i) acc += wsum[i];
        partial[((b * 5 + w) << 1) + qc] = acc;
    }
}

__global__ void finalize2(const float* __restrict__ partial, float* __restrict__ out) {
    int i = blockIdx.x * blockDim.x + threadIdx.x;
    if (i < 320)
        out[i] = partial[2 * i] + partial[2 * i + 1];
}

// =============================================================================
extern "C" void kernel_launch(void* const* d_in, const int* in_sizes, int n_in,
                              void* d_out, int out_size, void* d_ws, size_t ws_size,
                              hipStream_t stream) {
    const float* Q = (const float*)d_in[0];   // (64,64,32,32)
    const float* S = (const float*)d_in[1];   // (64,5,64,1024)
    float* out = (float*)d_out;               // (64,5)

    // fast-path ws layout: Qbf 8 MB | Sbf 41.9 MB | rnq 256 KB | partial 5 KB
    const size_t NEED = 8388608ull + 41943040ull + 262144ull + 5120ull;
    if (ws_size >= NEED) {
        uint4* Qbf    = (uint4*)d_ws;
        uint4* Sbf    = (uint4*)((char*)d_ws + 8388608ull);
        float* rnq    = (float*)((char*)d_ws + 8388608ull + 41943040ull);
        float* partial= (float*)((char*)d_ws + 8388608ull + 41943040ull + 262144ull);
        prep_q<<<256, 256, 0, stream>>>(Q, Qbf, rnq);
        prep_s<<<1280, 256, 0, stream>>>(S, Sbf);
        knn_main<<<dim3(4, 5, 64), 256, 0, stream>>>(Qbf, Sbf, rnq, partial);
        finalize4<<<2, 256, 0, stream>>>(partial, out);
    } else {
        float* rnq = (float*)d_ws;
        float* rns = rnq + 65536;
        float* partial = rns + 327680;
        norms_kernel<<<(65536 + 327680) / 256, 256, 0, stream>>>(Q, S, rnq, rns);
        knn_fb<<<dim3(2, 5, 64), 512, 0, stream>>>(Q, S, rnq, rns, partial);
        finalize2<<<2, 256, 0, stream>>>(partial, out);
    }
}

// Round 4
// 96.503 us; speedup vs baseline: 1.1251x; 1.0315x over previous
//
#include <hip/hip_runtime.h>
#include <hip/hip_bf16.h>

// LocalKNN: B=64, Way=5, D=64, Nq=1024, Ns=1024, K=3.
// out[b,w] = sum_q rnq[q] * sum(top3_s( <q_bq, shat_bws> ))
// Round 4: 3-deep ring prefetch (no copy; waitcnt lands 3 iters after issue)
//          + bijective XCD swizzle so qc-blocks sharing an S-slice share an L2.

using bf16x8 = __attribute__((ext_vector_type(8))) short;  // 8 bf16 = 4 VGPRs
using f32x4  = __attribute__((ext_vector_type(4))) float;

__device__ inline unsigned cvt_pk_bf16(float lo, float hi) {
    unsigned r;
    asm("v_cvt_pk_bf16_f32 %0, %1, %2" : "=v"(r) : "v"(lo), "v"(hi));
    return r;
}

__device__ inline uint4 pack8cvt(const float* v) {
    uint4 r;
    r.x = cvt_pk_bf16(v[0], v[1]);
    r.y = cvt_pk_bf16(v[2], v[3]);
    r.z = cvt_pk_bf16(v[4], v[5]);
    r.w = cvt_pk_bf16(v[6], v[7]);
    return r;
}

// branchless insert of v into sorted top-3 (t0>=t1>=t2): 1 max + 2 med3
#define INS(v, T0, T1, T2) do {                         \
    float _v = (v);                                     \
    float _n0 = fmaxf((T0), _v);                        \
    float _n1 = __builtin_amdgcn_fmed3f(_v, (T0), (T1));\
    float _n2 = __builtin_amdgcn_fmed3f(_v, (T1), (T2));\
    (T0) = _n0; (T1) = _n1; (T2) = _n2;                 \
} while (0)

// ============================= fast path =====================================
// Fragment layout: per 16-col tile, 128 uint4 slots; slot h*16 + r holds
// column (tile*16+r)'s elements d = 8h..8h+7 as 4 packed bf16-pairs.
// MFMA read: slot c*64 + lane -> lane holds col r=lane&15, k = c*32 + (lane>>4)*8 + j.

// ---- prep_all: raw Q/S -> bf16 fragments (+ rnq) ----------------------------
// blocks 0..255: Q (b = blk>>2); blocks 256..1535: S (bw = (blk-256)>>2)
__global__ __launch_bounds__(256) void prep_all(const float* __restrict__ Q,
                                                const float* __restrict__ S,
                                                uint4* __restrict__ Qbf,
                                                uint4* __restrict__ Sbf,
                                                float* __restrict__ rnq) {
    const int blk = blockIdx.x;
    if (blk < 256) {
        const int b = blk >> 2;
        const int col = ((blk & 3) << 8) + threadIdx.x;      // q in 0..1023
        const float* p = Q + (size_t)b * 65536 + col;
        float v[64];
        #pragma unroll
        for (int d = 0; d < 64; ++d) v[d] = p[(size_t)d << 10];
        float ss = 0.f;
        #pragma unroll
        for (int d = 0; d < 64; ++d) ss += v[d] * v[d];
        rnq[(b << 10) + col] = 1.0f / fmaxf(sqrtf(ss), 1e-12f);
        uint4* ob = Qbf + ((size_t)(b << 6) + (col >> 4)) * 128 + (col & 15);
        #pragma unroll
        for (int h = 0; h < 8; ++h)
            ob[h << 4] = pack8cvt(&v[h << 3]);
    } else {
        const int bw = (blk - 256) >> 2;
        const int col = ((blk & 3) << 8) + threadIdx.x;      // s in 0..1023
        const float* p = S + (size_t)bw * 65536 + col;
        float v[64];
        #pragma unroll
        for (int d = 0; d < 64; ++d) v[d] = p[(size_t)d << 10];
        float ss = 0.f;
        #pragma unroll
        for (int d = 0; d < 64; ++d) ss += v[d] * v[d];
        const float rs = 1.0f / fmaxf(sqrtf(ss), 1e-12f);
        #pragma unroll
        for (int d = 0; d < 64; ++d) v[d] *= rs;
        uint4* ob = Sbf + ((size_t)(bw << 6) + (col >> 4)) * 128 + (col & 15);
        #pragma unroll
        for (int h = 0; h < 8; ++h)
            ob[h << 4] = pack8cvt(&v[h << 3]);
    }
}

// ---- main: barrier-free fused GEMM + top-3 ---------------------------------
// 1-D grid 1280 (logical l: qc = l&3, bw = l>>2), block = 256 (4 waves).
// XCD swizzle: dispatch id d -> logical (d%8)*160 + d/8, so the 4 qc-blocks of
// each (b,w) run on one XCD and share its L2 copy of the S-slice (128 KB).
__global__ __launch_bounds__(256) void knn_main(const uint4* __restrict__ Qbf,
                                                const uint4* __restrict__ Sbf,
                                                const float* __restrict__ rnq,
                                                float* __restrict__ partial) {
    __shared__ float wsum[4];
    const int lin = blockIdx.x;
    const int l   = (lin & 7) * 160 + (lin >> 3);   // 1280 = 8*160, bijective
    const int qc  = l & 3;
    const int bw  = l >> 2;                          // b*5 + w
    const int b   = bw / 5;
    const int wv = threadIdx.x >> 6, lane = threadIdx.x & 63;

    const uint4* qb = Qbf + ((size_t)(b << 6) + (qc << 4) + (wv << 2)) * 128 + lane;
    bf16x8 bq[4][2];
    #pragma unroll
    for (int qt = 0; qt < 4; ++qt)
        #pragma unroll
        for (int c = 0; c < 2; ++c)
            bq[qt][c] = *reinterpret_cast<const bf16x8*>(&qb[qt * 128 + (c << 6)]);

    const uint4* sb = Sbf + (size_t)(bw << 6) * 128 + lane;

    float t0[4], t1[4], t2[4];
    #pragma unroll
    for (int qt = 0; qt < 4; ++qt) { t0[qt] = -1e30f; t1[qt] = -1e30f; t2[qt] = -1e30f; }

    // 3-deep ring prefetch: load directly into the slot consumed 3 iters later.
    bf16x8 abuf[4][2];
    #pragma unroll
    for (int i = 0; i < 3; ++i) {
        abuf[i][0] = *reinterpret_cast<const bf16x8*>(&sb[i * 128]);
        abuf[i][1] = *reinterpret_cast<const bf16x8*>(&sb[i * 128 + 64]);
    }
    #pragma unroll 4
    for (int st = 0; st < 64; ++st) {
        if (st + 3 < 64) {
            abuf[(st + 3) & 3][0] = *reinterpret_cast<const bf16x8*>(&sb[(st + 3) * 128]);
            abuf[(st + 3) & 3][1] = *reinterpret_cast<const bf16x8*>(&sb[(st + 3) * 128 + 64]);
        }
        #pragma unroll
        for (int qt = 0; qt < 4; ++qt) {
            f32x4 c = {0.f, 0.f, 0.f, 0.f};
            c = __builtin_amdgcn_mfma_f32_16x16x32_bf16(abuf[st & 3][0], bq[qt][0], c, 0, 0, 0);
            c = __builtin_amdgcn_mfma_f32_16x16x32_bf16(abuf[st & 3][1], bq[qt][1], c, 0, 0, 0);
            #pragma unroll
            for (int j = 0; j < 4; ++j)
                INS(c[j], t0[qt], t1[qt], t2[qt]);
        }
    }

    // merge top-3 across the 4 lane-groups sharing each q; apply rnq
    float s3 = 0.f;
    #pragma unroll
    for (int qt = 0; qt < 4; ++qt) {
        #pragma unroll
        for (int m = 16; m <= 32; m <<= 1) {
            float b0 = __shfl_xor(t0[qt], m);
            float b1 = __shfl_xor(t1[qt], m);
            float b2 = __shfl_xor(t2[qt], m);
            INS(b0, t0[qt], t1[qt], t2[qt]);
            INS(b1, t0[qt], t1[qt], t2[qt]);
            INS(b2, t0[qt], t1[qt], t2[qt]);
        }
        const int qg = (qc << 8) + (wv << 6) + (qt << 4) + (lane & 15);
        s3 += (t0[qt] + t1[qt] + t2[qt]) * rnq[(b << 10) + qg];
    }
    #pragma unroll
    for (int m = 1; m < 64; m <<= 1) s3 += __shfl_xor(s3, m);
    s3 *= 0.25f;                       // each q replicated over 4 lane-groups
    if (lane == 0) wsum[wv] = s3;
    __syncthreads();
    if (threadIdx.x == 0)
        partial[((size_t)bw << 2) + qc] = (wsum[0] + wsum[1]) + (wsum[2] + wsum[3]);
}

__global__ void finalize4(const float* __restrict__ partial, float* __restrict__ out) {
    int i = blockIdx.x * blockDim.x + threadIdx.x;
    if (i < 320)
        out[i] = (partial[4 * i] + partial[4 * i + 1]) +
                 (partial[4 * i + 2] + partial[4 * i + 3]);
}

// ============================ fallback path (round-2) ========================
__global__ void norms_kernel(const float* __restrict__ Q, const float* __restrict__ S,
                             float* __restrict__ rnq, float* __restrict__ rns) {
    int gid = blockIdx.x * blockDim.x + threadIdx.x;
    if (gid < 65536) {
        int b = gid >> 10, qi = gid & 1023;
        const float* p = Q + (size_t)b * 65536 + qi;
        float ss = 0.f;
        #pragma unroll
        for (int d = 0; d < 64; ++d) { float v = p[(size_t)d * 1024]; ss += v * v; }
        rnq[gid] = 1.0f / fmaxf(sqrtf(ss), 1e-12f);
    } else {
        int v = gid - 65536;
        int bw = v >> 10, si = v & 1023;
        const float* p = S + (size_t)bw * 65536 + si;
        float ss = 0.f;
        #pragma unroll
        for (int d = 0; d < 64; ++d) { float x = p[(size_t)d * 1024]; ss += x * x; }
        rns[v] = 1.0f / fmaxf(sqrtf(ss), 1e-12f);
    }
}

__global__ __launch_bounds__(512, 4) void knn_fb(
        const float* __restrict__ Q, const float* __restrict__ S,
        const float* __restrict__ rnq, const float* __restrict__ rns,
        float* __restrict__ partial) {
    __shared__ uint4 qfrag[16 * 128];
    __shared__ uint4 sfrag[2][4 * 128];
    __shared__ float wsum[8];

    const int qc = blockIdx.x, w = blockIdx.y, b = blockIdx.z;
    const int t = threadIdx.x, wv = t >> 6, lane = t & 63;

    const float* Qb   = Q + (size_t)b * 65536;
    const float* Sb   = S + (size_t)(b * 5 + w) * 65536;
    const float* rnqb = rnq + (b << 10);
    const float* rnsb = rns + ((b * 5 + w) << 10);

    bf16x8 bq[4][2];
    for (int ph = 0; ph < 2; ++ph) {
        for (int sub = 0; sub < 4; ++sub) {
            int qg = (qc << 9) + (ph << 8) + (sub << 6) + lane;
            float v[8];
            #pragma unroll
            for (int i = 0; i < 8; ++i)
                v[i] = Qb[(size_t)((wv << 3) + i) * 1024 + qg];
            qfrag[((sub << 2) + (lane >> 4)) * 128 + (wv << 4) + (lane & 15)] = pack8cvt(v);
        }
        __syncthreads();
        if ((wv >> 2) == ph) {
            #pragma unroll
            for (int qt = 0; qt < 4; ++qt)
                #pragma unroll
                for (int c = 0; c < 2; ++c)
                    bq[qt][c] = *reinterpret_cast<const bf16x8*>(
                        &qfrag[(((wv & 3) << 2) + qt) * 128 + (c << 6) + lane]);
        }
        __syncthreads();
    }

    {
        float sv[8]; float rs = rnsb[lane];
        #pragma unroll
        for (int i = 0; i < 8; ++i)
            sv[i] = Sb[(size_t)((wv << 3) + i) * 1024 + lane] * rs;
        sfrag[0][(lane >> 4) * 128 + (wv << 4) + (lane & 15)] = pack8cvt(sv);
    }
    __syncthreads();

    float t0[4], t1[4], t2[4];
    #pragma unroll
    for (int qt = 0; qt < 4; ++qt) { t0[qt] = -1e30f; t1[qt] = -1e30f; t2[qt] = -1e30f; }
    int cur = 0;
    const float* sp = Sb + ((wv << 3) << 10) + lane;

    for (int blk = 0; blk < 16; ++blk) {
        float sv[8]; float rs;
        if (blk < 15) {
            const int sb_ = (blk + 1) << 6;
            rs = rnsb[sb_ + lane];
            #pragma unroll
            for (int i = 0; i < 8; ++i)
                sv[i] = sp[(size_t)(i << 10) + sb_];
        }
        #pragma unroll
        for (int st = 0; st < 4; ++st) {
            bf16x8 a0 = *reinterpret_cast<const bf16x8*>(&sfrag[cur][st * 128 + lane]);
            bf16x8 a1 = *reinterpret_cast<const bf16x8*>(&sfrag[cur][st * 128 + 64 + lane]);
            #pragma unroll
            for (int qt = 0; qt < 4; ++qt) {
                f32x4 c = {0.f, 0.f, 0.f, 0.f};
                c = __builtin_amdgcn_mfma_f32_16x16x32_bf16(a0, bq[qt][0], c, 0, 0, 0);
                c = __builtin_amdgcn_mfma_f32_16x16x32_bf16(a1, bq[qt][1], c, 0, 0, 0);
                #pragma unroll
                for (int j = 0; j < 4; ++j)
                    INS(c[j], t0[qt], t1[qt], t2[qt]);
            }
        }
        if (blk < 15) {
            #pragma unroll
            for (int i = 0; i < 8; ++i) sv[i] *= rs;
            sfrag[cur ^ 1][(lane >> 4) * 128 + (wv << 4) + (lane & 15)] = pack8cvt(sv);
        }
        __syncthreads();
        cur ^= 1;
    }

    float s3 = 0.f;
    #pragma unroll
    for (int qt = 0; qt < 4; ++qt) {
        #pragma unroll
        for (int m = 16; m <= 32; m <<= 1) {
            float b0 = __shfl_xor(t0[qt], m);
            float b1 = __shfl_xor(t1[qt], m);
            float b2 = __shfl_xor(t2[qt], m);
            INS(b0, t0[qt], t1[qt], t2[qt]);
            INS(b1, t0[qt], t1[qt], t2[qt]);
            INS(b2, t0[qt], t1[qt], t2[qt]);
        }
        int qg = (qc << 9) + (wv << 6) + (qt << 4) + (lane & 15);
        s3 += (t0[qt] + t1[qt] + t2[qt]) * rnqb[qg];
    }
    #pragma unroll
    for (int m = 1; m < 64; m <<= 1) s3 += __shfl_xor(s3, m);
    s3 *= 0.25f;
    if (lane == 0) wsum[wv] = s3;
    __syncthreads();
    if (t == 0) {
        float acc = 0.f;
        #pragma unroll
        for (int i = 0; i < 8; ++i) acc += wsum[i];
        partial[((b * 5 + w) << 1) + qc] = acc;
    }
}

__global__ void finalize2(const float* __restrict__ partial, float* __restrict__ out) {
    int i = blockIdx.x * blockDim.x + threadIdx.x;
    if (i < 320)
        out[i] = partial[2 * i] + partial[2 * i + 1];
}

// =============================================================================
extern "C" void kernel_launch(void* const* d_in, const int* in_sizes, int n_in,
                              void* d_out, int out_size, void* d_ws, size_t ws_size,
                              hipStream_t stream) {
    const float* Q = (const float*)d_in[0];   // (64,64,32,32)
    const float* S = (const float*)d_in[1];   // (64,5,64,1024)
    float* out = (float*)d_out;               // (64,5)

    // fast-path ws layout: Qbf 8 MB | Sbf 41.9 MB | rnq 256 KB | partial 5 KB
    const size_t NEED = 8388608ull + 41943040ull + 262144ull + 5120ull;
    if (ws_size >= NEED) {
        uint4* Qbf    = (uint4*)d_ws;
        uint4* Sbf    = (uint4*)((char*)d_ws + 8388608ull);
        float* rnq    = (float*)((char*)d_ws + 8388608ull + 41943040ull);
        float* partial= (float*)((char*)d_ws + 8388608ull + 41943040ull + 262144ull);
        prep_all<<<1536, 256, 0, stream>>>(Q, S, Qbf, Sbf, rnq);
        knn_main<<<1280, 256, 0, stream>>>(Qbf, Sbf, rnq, partial);
        finalize4<<<2, 256, 0, stream>>>(partial, out);
    } else {
        float* rnq = (float*)d_ws;
        float* rns = rnq + 65536;
        float* partial = rns + 327680;
        norms_kernel<<<(65536 + 327680) / 256, 256, 0, stream>>>(Q, S, rnq, rns);
        knn_fb<<<dim3(2, 5, 64), 512, 0, stream>>>(Q, S, rnq, rns, partial);
        finalize2<<<2, 256, 0, stream>>>(partial, out);
    }
}